// Round 1
// baseline (827.746 us; speedup 1.0000x reference)
//
#include <hip/hip_runtime.h>
#include <hip/hip_bf16.h>
#include <math.h>

#define NN 50000
#define NE 800000
#define NET (NE + NN)   // edges + self loops
#define FIN 310
#define HD 128
#define NHID 64
#define NCLS 2
#define NG 128
#define NEG_SLOPE 0.2f

#define SELU_SCALE 1.0507009873554804934193349852946f
#define SELU_ALPHA 1.6732632423543772848170429916717f

__device__ __forceinline__ float selu(float x) {
    return SELU_SCALE * (x > 0.f ? x : SELU_ALPHA * (expf(x) - 1.f));
}
__device__ __forceinline__ float lrelu(float x) {
    return x > 0.f ? x : NEG_SLOPE * x;
}

// ---------------- CSR build ----------------

__global__ void k_init_deg(int* deg) {
    int i = blockIdx.x * blockDim.x + threadIdx.x;
    if (i < NN) deg[i] = 0;
}

__global__ void k_hist(const int* __restrict__ ei, int* __restrict__ deg) {
    int i = blockIdx.x * blockDim.x + threadIdx.x;
    if (i >= NET) return;
    int d = (i < NE) ? ei[NE + i] : (i - NE);
    atomicAdd(&deg[d], 1);
}

// single-block exclusive scan; degcur holds deg on входе, cursor (=start) on exit
__global__ void k_scan(int* __restrict__ degcur, int* __restrict__ indptr) {
    __shared__ int sm[1024];
    __shared__ int carry_s;
    int tid = threadIdx.x;
    if (tid == 0) carry_s = 0;
    __syncthreads();
    for (int base = 0; base < NN; base += 1024) {
        int i = base + tid;
        int v = (i < NN) ? degcur[i] : 0;
        sm[tid] = v;
        __syncthreads();
        for (int off = 1; off < 1024; off <<= 1) {
            int t = (tid >= off) ? sm[tid - off] : 0;
            __syncthreads();
            sm[tid] += t;
            __syncthreads();
        }
        int excl = sm[tid] - v;
        int carry = carry_s;
        if (i < NN) {
            indptr[i] = carry + excl;
            degcur[i] = carry + excl;   // becomes the scatter cursor
        }
        __syncthreads();
        if (tid == 0) carry_s = carry + sm[1023];
        __syncthreads();
    }
    if (tid == 0) indptr[NN] = carry_s;
}

__global__ void k_scatter(const int* __restrict__ ei, int* __restrict__ cursor,
                          int* __restrict__ csr_src) {
    int i = blockIdx.x * blockDim.x + threadIdx.x;
    if (i >= NET) return;
    int s, d;
    if (i < NE) { s = ei[i]; d = ei[NE + i]; }
    else        { s = i - NE; d = s; }
    int pos = atomicAdd(&cursor[d], 1);
    csr_src[pos] = s;
}

// ---------------- GEMM (fp32, 64x64 tile, 4x4 per thread) ----------------

__global__ __launch_bounds__(256) void k_gemm(const float* __restrict__ A,
                                              const float* __restrict__ B,
                                              float* __restrict__ C,
                                              int M, int K, int Nc) {
    __shared__ float As[64][17];
    __shared__ float Bs[16][65];
    int tid = threadIdx.x;
    int row0 = blockIdx.x * 64;
    int col0 = blockIdx.y * 64;
    int tr = (tid >> 4) << 2;   // 0,4,..,60
    int tc = (tid & 15) << 2;
    float acc[4][4] = {};
    for (int k0 = 0; k0 < K; k0 += 16) {
#pragma unroll
        for (int l = 0; l < 4; ++l) {
            int lin = tid + 256 * l;
            int r = lin >> 4, kk = lin & 15;
            int gr = row0 + r, gk = k0 + kk;
            As[r][kk] = (gr < M && gk < K) ? A[(size_t)gr * K + gk] : 0.f;
        }
#pragma unroll
        for (int l = 0; l < 4; ++l) {
            int lin = tid + 256 * l;
            int kk = lin >> 6, c = lin & 63;
            int gk = k0 + kk, gc = col0 + c;
            Bs[kk][c] = (gk < K && gc < Nc) ? B[(size_t)gk * Nc + gc] : 0.f;
        }
        __syncthreads();
#pragma unroll
        for (int kk = 0; kk < 16; ++kk) {
            float av[4], bv[4];
#pragma unroll
            for (int i = 0; i < 4; ++i) av[i] = As[tr + i][kk];
#pragma unroll
            for (int j = 0; j < 4; ++j) bv[j] = Bs[kk][tc + j];
#pragma unroll
            for (int i = 0; i < 4; ++i)
#pragma unroll
                for (int j = 0; j < 4; ++j)
                    acc[i][j] += av[i] * bv[j];
        }
        __syncthreads();
    }
#pragma unroll
    for (int i = 0; i < 4; ++i) {
        int gr = row0 + tr + i;
        if (gr >= M) continue;
#pragma unroll
        for (int j = 0; j < 4; ++j) {
            int gc = col0 + tc + j;
            if (gc < Nc) C[(size_t)gr * Nc + gc] = acc[i][j];
        }
    }
}

// ---------------- per-node attention dots ----------------

__global__ __launch_bounds__(256) void k_dots(const float* __restrict__ h,
                                              const float* __restrict__ a_src,
                                              const float* __restrict__ a_dst,
                                              float* __restrict__ asrc,
                                              float* __restrict__ adst) {
    int gid = blockIdx.x * blockDim.x + threadIdx.x;
    int node = gid >> 6;
    int lane = threadIdx.x & 63;
    if (node >= NN) return;
    const float* row = h + (size_t)node * HD;
    float v1 = row[lane] * a_src[lane] + row[lane + 64] * a_src[lane + 64];
    float v2 = row[lane] * a_dst[lane] + row[lane + 64] * a_dst[lane + 64];
    for (int off = 32; off; off >>= 1) {
        v1 += __shfl_down(v1, off);
        v2 += __shfl_down(v2, off);
    }
    if (lane == 0) { asrc[node] = v1; adst[node] = v2; }
}

// ---------------- GAT aggregation: one wave per node ----------------

__global__ __launch_bounds__(256) void k_gat(const float* __restrict__ h,
                                             const float* __restrict__ asrc,
                                             const float* __restrict__ adst,
                                             const int* __restrict__ indptr,
                                             const int* __restrict__ csr_src,
                                             const float* __restrict__ bias,
                                             float* __restrict__ out) {
    int node = blockIdx.x * 4 + (threadIdx.x >> 6);
    int lane = threadIdx.x & 63;
    if (node >= NN) return;
    int start = indptr[node], end = indptr[node + 1];
    float adsti = adst[node];

    // pass 1: max over incoming edges (lanes parallel)
    float m = -1e30f;
    for (int j = start + lane; j < end; j += 64)
        m = fmaxf(m, lrelu(asrc[csr_src[j]] + adsti));
    for (int off = 32; off; off >>= 1)
        m = fmaxf(m, __shfl_down(m, off));
    m = __shfl(m, 0);

    // pass 2: accumulate numerator / denominator
    float den = 0.f;
    float ax = 0.f, ay = 0.f;
    for (int j = start; j < end; ++j) {
        int s = csr_src[j];
        float e = lrelu(asrc[s] + adsti);
        float p = expf(e - m);
        den += p;
        const float2 hv = *(const float2*)(h + (size_t)s * HD + lane * 2);
        ax += p * hv.x;
        ay += p * hv.y;
    }
    float inv = 1.f / den;
    int c = lane * 2;
    out[(size_t)node * HD + c]     = selu(ax * inv + bias[c]);
    out[(size_t)node * HD + c + 1] = selu(ay * inv + bias[c + 1]);
}

// ---------------- pooling ----------------

__device__ __forceinline__ int lower_bound_i(const int* a, int n, int key) {
    int lo = 0, hi = n;
    while (lo < hi) {
        int mid = (lo + hi) >> 1;
        if (a[mid] < key) lo = mid + 1; else hi = mid;
    }
    return lo;
}

__global__ __launch_bounds__(128) void k_pool(const float* __restrict__ x,
                                              const int* __restrict__ batch,
                                              float* __restrict__ pooled) {
    int g = blockIdx.x;
    int t = threadIdx.x;
    __shared__ int lo_s, hi_s;
    if (t == 0) {
        lo_s = lower_bound_i(batch, NN, g);
        hi_s = lower_bound_i(batch, NN, g + 1);
    }
    __syncthreads();
    int lo = lo_s, hi = hi_s;
    float acc = 0.f;
    for (int n = lo; n < hi; ++n) acc += x[(size_t)n * HD + t];
    float cnt = fmaxf((float)(hi - lo), 1.0f);
    pooled[g * HD + t] = selu(acc / cnt);
}

// ---------------- FC head ----------------

__global__ __launch_bounds__(64) void k_fc(const float* __restrict__ pooled,
                                           const float* __restrict__ w1,
                                           const float* __restrict__ b1,
                                           const float* __restrict__ w2,
                                           const float* __restrict__ b2,
                                           float* __restrict__ out) {
    int g = blockIdx.x;
    int t = threadIdx.x;  // 64
    const float* p = pooled + g * HD;
    float z = 0.f;
    for (int k = 0; k < HD; ++k) z += p[k] * w1[k * NHID + t];
    z = selu(z + b1[t]);
    float p0 = z * w2[t * NCLS + 0];
    float p1 = z * w2[t * NCLS + 1];
    for (int off = 32; off; off >>= 1) {
        p0 += __shfl_down(p0, off);
        p1 += __shfl_down(p1, off);
    }
    if (t == 0) {
        float l0 = p0 + b2[0], l1 = p1 + b2[1];
        float m = fmaxf(l0, l1);
        float lse = m + logf(expf(l0 - m) + expf(l1 - m));
        out[g * NCLS + 0] = l0 - lse;
        out[g * NCLS + 1] = l1 - lse;
    }
}

// ---------------- launch ----------------

static inline size_t align_up(size_t v, size_t a) { return (v + a - 1) / a * a; }

extern "C" void kernel_launch(void* const* d_in, const int* in_sizes, int n_in,
                              void* d_out, int out_size, void* d_ws, size_t ws_size,
                              hipStream_t stream) {
    const float* x      = (const float*)d_in[0];
    const int*   ei     = (const int*)d_in[1];
    const int*   batch  = (const int*)d_in[2];
    const float* W1     = (const float*)d_in[3];
    const float* a_src1 = (const float*)d_in[4];
    const float* a_dst1 = (const float*)d_in[5];
    const float* b1     = (const float*)d_in[6];
    const float* W2     = (const float*)d_in[7];
    const float* a_src2 = (const float*)d_in[8];
    const float* a_dst2 = (const float*)d_in[9];
    const float* b2     = (const float*)d_in[10];
    const float* fc1_w  = (const float*)d_in[11];
    const float* fc1_b  = (const float*)d_in[12];
    const float* fc2_w  = (const float*)d_in[13];
    const float* fc2_b  = (const float*)d_in[14];
    float* out = (float*)d_out;

    char* ws = (char*)d_ws;
    size_t off = 0;
    float* h1   = (float*)(ws + off); off = align_up(off + (size_t)NN * HD * 4, 256);
    float* o1   = (float*)(ws + off); off = align_up(off + (size_t)NN * HD * 4, 256);
    float* asrc = (float*)(ws + off); off = align_up(off + (size_t)NN * 4, 256);
    float* adst = (float*)(ws + off); off = align_up(off + (size_t)NN * 4, 256);
    int* indptr = (int*)(ws + off);   off = align_up(off + (size_t)(NN + 1) * 4, 256);
    int* cursor = (int*)(ws + off);   off = align_up(off + (size_t)NN * 4, 256);
    int* csr    = (int*)(ws + off);   off = align_up(off + (size_t)NET * 4, 256);
    float* pooled = (float*)(ws + off); off = align_up(off + (size_t)NG * HD * 4, 256);
    (void)ws_size;

    // CSR build (by dst, includes self loops)
    k_init_deg<<<(NN + 255) / 256, 256, 0, stream>>>(cursor);
    k_hist<<<(NET + 255) / 256, 256, 0, stream>>>(ei, cursor);
    k_scan<<<1, 1024, 0, stream>>>(cursor, indptr);
    k_scatter<<<(NET + 255) / 256, 256, 0, stream>>>(ei, cursor, csr);

    // Layer 1
    dim3 g1((NN + 63) / 64, (HD + 63) / 64);
    k_gemm<<<g1, 256, 0, stream>>>(x, W1, h1, NN, FIN, HD);
    k_dots<<<(NN * 64 + 255) / 256, 256, 0, stream>>>(h1, a_src1, a_dst1, asrc, adst);
    k_gat<<<(NN + 3) / 4, 256, 0, stream>>>(h1, asrc, adst, indptr, csr, b1, o1);

    // Layer 2 (h2 overwrites h1; out2 overwrites o1)
    k_gemm<<<g1, 256, 0, stream>>>(o1, W2, h1, NN, HD, HD);
    k_dots<<<(NN * 64 + 255) / 256, 256, 0, stream>>>(h1, a_src2, a_dst2, asrc, adst);
    k_gat<<<(NN + 3) / 4, 256, 0, stream>>>(h1, asrc, adst, indptr, csr, b2, o1);

    // Pool + FC head
    k_pool<<<NG, 128, 0, stream>>>(o1, batch, pooled);
    k_fc<<<NG, 64, 0, stream>>>(pooled, fc1_w, fc1_b, fc2_w, fc2_b, out);
}

// Round 2
// 421.002 us; speedup vs baseline: 1.9661x; 1.9661x over previous
//
#include <hip/hip_runtime.h>
#include <hip/hip_bf16.h>
#include <math.h>

#define NN 50000
#define NE 800000
#define NET (NE + NN)   // edges + self loops
#define FIN 310
#define HD 128
#define NHID 64
#define NCLS 2
#define NG 128
#define NEG_SLOPE 0.2f

#define SELU_SCALE 1.0507009873554804934193349852946f
#define SELU_ALPHA 1.6732632423543772848170429916717f

typedef short bf16x8 __attribute__((ext_vector_type(8)));
typedef float f32x4 __attribute__((ext_vector_type(4)));

__device__ __forceinline__ float selu(float x) {
    return SELU_SCALE * (x > 0.f ? x : SELU_ALPHA * (expf(x) - 1.f));
}
__device__ __forceinline__ float lrelu(float x) {
    return x > 0.f ? x : NEG_SLOPE * x;
}
__device__ __forceinline__ unsigned short f2bf(float f) {
    unsigned int u = __float_as_uint(f);
    u = (u + 0x7fffu + ((u >> 16) & 1u)) >> 16;
    return (unsigned short)u;
}

// ---------------- CSR build ----------------

__global__ void k_init_deg(int* deg) {
    int i = blockIdx.x * blockDim.x + threadIdx.x;
    if (i < NN) deg[i] = 0;
}

__global__ void k_hist(const int* __restrict__ ei, int* __restrict__ deg) {
    int i = blockIdx.x * blockDim.x + threadIdx.x;
    if (i >= NET) return;
    int d = (i < NE) ? ei[NE + i] : (i - NE);
    atomicAdd(&deg[d], 1);
}

// 3-phase scan: local block scan -> scan block sums -> add offsets
__global__ __launch_bounds__(1024) void k_scan_local(const int* __restrict__ deg,
                                                     int* __restrict__ indptr,
                                                     int* __restrict__ bsum) {
    int t = threadIdx.x;
    int i = blockIdx.x * 1024 + t;
    int lane = t & 63, w = t >> 6;
    int v = (i < NN) ? deg[i] : 0;
    int x = v;
#pragma unroll
    for (int off = 1; off < 64; off <<= 1) {
        int tmp = __shfl_up(x, off);
        if (lane >= off) x += tmp;
    }
    __shared__ int wsum[16];
    if (lane == 63) wsum[w] = x;
    __syncthreads();
    if (t < 16) {
        int y = wsum[t];
#pragma unroll
        for (int off = 1; off < 16; off <<= 1) {
            int tmp = __shfl_up(y, off);
            if (t >= off) y += tmp;
        }
        wsum[t] = y;
    }
    __syncthreads();
    int incl = x + (w ? wsum[w - 1] : 0);
    if (i < NN) indptr[i] = incl - v;   // block-local exclusive
    if (t == 1023) bsum[blockIdx.x] = incl;
}

__global__ __launch_bounds__(64) void k_scan_sums(int* __restrict__ bsum,
                                                  int* __restrict__ boff,
                                                  int* __restrict__ indptr, int nb) {
    int t = threadIdx.x;
    int v = (t < nb) ? bsum[t] : 0;
    int x = v;
#pragma unroll
    for (int off = 1; off < 64; off <<= 1) {
        int tmp = __shfl_up(x, off);
        if (t >= off) x += tmp;
    }
    if (t < nb) boff[t] = x - v;
    if (t == nb - 1) indptr[NN] = x;
}

__global__ __launch_bounds__(1024) void k_scan_add(int* __restrict__ indptr,
                                                   const int* __restrict__ boff,
                                                   int* __restrict__ cursor) {
    int i = blockIdx.x * 1024 + threadIdx.x;
    if (i < NN) {
        int val = indptr[i] + boff[blockIdx.x];
        indptr[i] = val;
        cursor[i] = val;
    }
}

__global__ void k_scatter(const int* __restrict__ ei, int* __restrict__ cursor,
                          int* __restrict__ csr_src) {
    int i = blockIdx.x * blockDim.x + threadIdx.x;
    if (i >= NET) return;
    int s, d;
    if (i < NE) { s = ei[i]; d = ei[NE + i]; }
    else        { s = i - NE; d = s; }
    int pos = atomicAdd(&cursor[d], 1);
    csr_src[pos] = s;
}

// ---------------- W cast + transpose: Bt[n][k] = bf16(W[k][n]) ----------------

__global__ void k_castT(const float* __restrict__ W, unsigned short* __restrict__ Bt,
                        int K, int Kp) {
    int i = blockIdx.x * blockDim.x + threadIdx.x;
    if (i >= 128 * Kp) return;
    int n = i / Kp, k = i % Kp;
    Bt[i] = (k < K) ? f2bf(W[(size_t)k * HD + n]) : (unsigned short)0;
}

// ---------------- MFMA bf16 GEMM: C[M,128] = A[M,K] @ B[K,128], fused att-dots -----

__global__ __launch_bounds__(256) void k_gemm(const float* __restrict__ A,
                                              const unsigned short* __restrict__ Bt,
                                              float* __restrict__ C,
                                              float* __restrict__ asrcp,
                                              float* __restrict__ adstp,
                                              const float* __restrict__ a_src,
                                              const float* __restrict__ a_dst,
                                              int M, int K, int Kp) {
    __shared__ unsigned short As[64][40];
    __shared__ unsigned short Bs[128][40];
    __shared__ float a1s[HD], a2s[HD];
    int t = threadIdx.x;
    int lane = t & 63, w = t >> 6;
    int quad = lane >> 4, l16 = lane & 15;
    int r0 = blockIdx.x * 64;

    if (t < HD) a1s[t] = a_src[t];
    else a2s[t - HD] = a_dst[t - HD];

    f32x4 acc[8] = {};

    int arow = t >> 4;          // 0..15 (+16*pass)
    int acol = (t & 15) * 2;    // 0..30
    int brow = t >> 1;          // 0..127
    int bcol = (t & 1) * 16;    // 0 or 16

    for (int k0 = 0; k0 < Kp; k0 += 32) {
        // stage A (fp32 -> bf16), 4 passes of 16 rows
#pragma unroll
        for (int p = 0; p < 4; ++p) {
            int rl = arow + p * 16;
            int gr = r0 + rl;
            int gk = k0 + acol;
            float2 v = make_float2(0.f, 0.f);
            if (gr < M) {
                if (gk + 1 < K) v = *(const float2*)(A + (size_t)gr * K + gk);
                else if (gk < K) v.x = A[(size_t)gr * K + gk];
            }
            ushort2 b;
            b.x = f2bf(v.x); b.y = f2bf(v.y);
            *(ushort2*)&As[rl][acol] = b;
        }
        // stage B (already bf16, transposed): 32 bytes per thread
        {
            const unsigned short* src = Bt + (size_t)brow * Kp + k0 + bcol;
            uint4 u0 = *(const uint4*)(src);
            uint4 u1 = *(const uint4*)(src + 8);
            *(uint4*)&Bs[brow][bcol] = u0;
            *(uint4*)&Bs[brow][bcol + 8] = u1;
        }
        __syncthreads();
        bf16x8 af = *(bf16x8*)&As[w * 16 + l16][quad * 8];
#pragma unroll
        for (int nt = 0; nt < 8; ++nt) {
            bf16x8 bfr = *(bf16x8*)&Bs[nt * 16 + l16][quad * 8];
            acc[nt] = __builtin_amdgcn_mfma_f32_16x16x32_bf16(af, bfr, acc[nt], 0, 0, 0);
        }
        __syncthreads();
    }

    int gr_base = r0 + w * 16 + quad * 4;
    // store C
#pragma unroll
    for (int r = 0; r < 4; ++r) {
        int gr = gr_base + r;
        if (gr < M) {
#pragma unroll
            for (int nt = 0; nt < 8; ++nt)
                C[(size_t)gr * HD + nt * 16 + l16] = acc[nt][r];
        }
    }
    // fused attention dots: asrc[row] = h_row . a_src ; adst likewise
#pragma unroll
    for (int r = 0; r < 4; ++r) {
        float s1 = 0.f, s2 = 0.f;
#pragma unroll
        for (int nt = 0; nt < 8; ++nt) {
            int c = nt * 16 + l16;
            float v = acc[nt][r];
            s1 += v * a1s[c];
            s2 += v * a2s[c];
        }
#pragma unroll
        for (int off = 1; off < 16; off <<= 1) {
            s1 += __shfl_xor(s1, off);
            s2 += __shfl_xor(s2, off);
        }
        int gr = gr_base + r;
        if (l16 == 0 && gr < M) { asrcp[gr] = s1; adstp[gr] = s2; }
    }
}

// ---------------- GAT aggregation: one wave per node, 4x unrolled ----------------

__global__ __launch_bounds__(256) void k_gat(const float* __restrict__ h,
                                             const float* __restrict__ asrc,
                                             const float* __restrict__ adst,
                                             const int* __restrict__ indptr,
                                             const int* __restrict__ csr,
                                             const float* __restrict__ bias,
                                             float* __restrict__ out) {
    int node = blockIdx.x * 4 + (threadIdx.x >> 6);
    int lane = threadIdx.x & 63;
    if (node >= NN) return;
    int start = indptr[node], end = indptr[node + 1];
    int deg = end - start;
    float adsti = adst[node];

    // cache first 64 edges in registers (coalesced loads)
    int s_l = 0; float e_l = -1e30f;
    if (lane < deg) {
        s_l = csr[start + lane];
        e_l = lrelu(asrc[s_l] + adsti);
    }
    float m = e_l;
    for (int j = start + 64 + lane; j < end; j += 64)
        m = fmaxf(m, lrelu(asrc[csr[j]] + adsti));
#pragma unroll
    for (int off = 32; off; off >>= 1)
        m = fmaxf(m, __shfl_xor(m, off));

    float den = 0.f, ax = 0.f, ay = 0.f;
    for (int jj = 0; jj < deg; jj += 4) {
        float px[4]; float2 hv[4];
#pragma unroll
        for (int u = 0; u < 4; ++u) {
            int j = jj + u;
            if (j < deg) {
                int s; float e;
                if (j < 64) { s = __shfl(s_l, j); e = __shfl(e_l, j); }
                else        { s = csr[start + j]; e = lrelu(asrc[s] + adsti); }
                px[u] = __expf(e - m);
                hv[u] = *(const float2*)(h + (size_t)s * HD + lane * 2);
            } else {
                px[u] = 0.f;
                hv[u] = make_float2(0.f, 0.f);
            }
        }
#pragma unroll
        for (int u = 0; u < 4; ++u) {
            den += px[u];
            ax += px[u] * hv[u].x;
            ay += px[u] * hv[u].y;
        }
    }
    float inv = 1.f / den;
    int c = lane * 2;
    out[(size_t)node * HD + c]     = selu(ax * inv + bias[c]);
    out[(size_t)node * HD + c + 1] = selu(ay * inv + bias[c + 1]);
}

// ---------------- pooling ----------------

__device__ __forceinline__ int lower_bound_i(const int* a, int n, int key) {
    int lo = 0, hi = n;
    while (lo < hi) {
        int mid = (lo + hi) >> 1;
        if (a[mid] < key) lo = mid + 1; else hi = mid;
    }
    return lo;
}

__global__ __launch_bounds__(512) void k_pool(const float* __restrict__ x,
                                              const int* __restrict__ batch,
                                              float* __restrict__ pooled) {
    int g = blockIdx.x;
    int t = threadIdx.x;
    __shared__ int lo_s, hi_s;
    __shared__ float red[512];
    if (t == 0) {
        lo_s = lower_bound_i(batch, NN, g);
        hi_s = lower_bound_i(batch, NN, g + 1);
    }
    __syncthreads();
    int lo = lo_s, hi = hi_s;
    float acc = 0.f;
    for (int n = lo + (t >> 7); n < hi; n += 4)
        acc += x[(size_t)n * HD + (t & 127)];
    red[t] = acc;
    __syncthreads();
    if (t < 128) {
        float v = red[t] + red[t + 128] + red[t + 256] + red[t + 384];
        pooled[g * HD + t] = selu(v / fmaxf((float)(hi - lo), 1.f));
    }
}

// ---------------- FC head ----------------

__global__ __launch_bounds__(64) void k_fc(const float* __restrict__ pooled,
                                           const float* __restrict__ w1,
                                           const float* __restrict__ b1,
                                           const float* __restrict__ w2,
                                           const float* __restrict__ b2,
                                           float* __restrict__ out) {
    int g = blockIdx.x;
    int t = threadIdx.x;  // 64
    const float* p = pooled + g * HD;
    float z = 0.f;
    for (int k = 0; k < HD; ++k) z += p[k] * w1[k * NHID + t];
    z = selu(z + b1[t]);
    float p0 = z * w2[t * NCLS + 0];
    float p1 = z * w2[t * NCLS + 1];
    for (int off = 32; off; off >>= 1) {
        p0 += __shfl_down(p0, off);
        p1 += __shfl_down(p1, off);
    }
    if (t == 0) {
        float l0 = p0 + b2[0], l1 = p1 + b2[1];
        float m = fmaxf(l0, l1);
        float lse = m + logf(expf(l0 - m) + expf(l1 - m));
        out[g * NCLS + 0] = l0 - lse;
        out[g * NCLS + 1] = l1 - lse;
    }
}

// ---------------- launch ----------------

static inline size_t align_up(size_t v, size_t a) { return (v + a - 1) / a * a; }

extern "C" void kernel_launch(void* const* d_in, const int* in_sizes, int n_in,
                              void* d_out, int out_size, void* d_ws, size_t ws_size,
                              hipStream_t stream) {
    const float* x      = (const float*)d_in[0];
    const int*   ei     = (const int*)d_in[1];
    const int*   batch  = (const int*)d_in[2];
    const float* W1     = (const float*)d_in[3];
    const float* a_src1 = (const float*)d_in[4];
    const float* a_dst1 = (const float*)d_in[5];
    const float* b1     = (const float*)d_in[6];
    const float* W2     = (const float*)d_in[7];
    const float* a_src2 = (const float*)d_in[8];
    const float* a_dst2 = (const float*)d_in[9];
    const float* b2     = (const float*)d_in[10];
    const float* fc1_w  = (const float*)d_in[11];
    const float* fc1_b  = (const float*)d_in[12];
    const float* fc2_w  = (const float*)d_in[13];
    const float* fc2_b  = (const float*)d_in[14];
    float* out = (float*)d_out;

    const int KP1 = 320;  // 310 padded to 32
    const int KP2 = 128;

    char* ws = (char*)d_ws;
    size_t off = 0;
    float* h1   = (float*)(ws + off); off = align_up(off + (size_t)NN * HD * 4, 256);
    float* o1   = (float*)(ws + off); off = align_up(off + (size_t)NN * HD * 4, 256);
    float* asrc = (float*)(ws + off); off = align_up(off + (size_t)NN * 4, 256);
    float* adst = (float*)(ws + off); off = align_up(off + (size_t)NN * 4, 256);
    int* indptr = (int*)(ws + off);   off = align_up(off + (size_t)(NN + 1) * 4, 256);
    int* cursor = (int*)(ws + off);   off = align_up(off + (size_t)NN * 4, 256);
    int* csr    = (int*)(ws + off);   off = align_up(off + (size_t)NET * 4, 256);
    float* pooled = (float*)(ws + off); off = align_up(off + (size_t)NG * HD * 4, 256);
    unsigned short* W1t = (unsigned short*)(ws + off); off = align_up(off + (size_t)HD * KP1 * 2, 256);
    unsigned short* W2t = (unsigned short*)(ws + off); off = align_up(off + (size_t)HD * KP2 * 2, 256);
    int* bsum = (int*)(ws + off); off = align_up(off + 64 * 4, 256);
    int* boff = (int*)(ws + off); off = align_up(off + 64 * 4, 256);
    (void)ws_size;

    const int NB = (NN + 1023) / 1024;  // 49

    // CSR build (by dst, includes self loops)
    k_init_deg<<<(NN + 255) / 256, 256, 0, stream>>>(cursor);
    k_hist<<<(NET + 255) / 256, 256, 0, stream>>>(ei, cursor);
    k_scan_local<<<NB, 1024, 0, stream>>>(cursor, indptr, bsum);
    k_scan_sums<<<1, 64, 0, stream>>>(bsum, boff, indptr, NB);
    k_scan_add<<<NB, 1024, 0, stream>>>(indptr, boff, cursor);
    k_scatter<<<(NET + 255) / 256, 256, 0, stream>>>(ei, cursor, csr);

    // weight cast+transpose
    k_castT<<<(HD * KP1 + 255) / 256, 256, 0, stream>>>(W1, W1t, FIN, KP1);
    k_castT<<<(HD * KP2 + 255) / 256, 256, 0, stream>>>(W2, W2t, HD, KP2);

    int gblocks = (NN + 63) / 64;  // 782

    // Layer 1
    k_gemm<<<gblocks, 256, 0, stream>>>(x, W1t, h1, asrc, adst, a_src1, a_dst1, NN, FIN, KP1);
    k_gat<<<(NN + 3) / 4, 256, 0, stream>>>(h1, asrc, adst, indptr, csr, b1, o1);

    // Layer 2
    k_gemm<<<gblocks, 256, 0, stream>>>(o1, W2t, h1, asrc, adst, a_src2, a_dst2, NN, HD, KP2);
    k_gat<<<(NN + 3) / 4, 256, 0, stream>>>(h1, asrc, adst, indptr, csr, b2, o1);

    // Pool + FC head
    k_pool<<<NG, 512, 0, stream>>>(o1, batch, pooled);
    k_fc<<<NG, 64, 0, stream>>>(pooled, fc1_w, fc1_b, fc2_w, fc2_b, out);
}